// Round 1
// baseline (265.832 us; speedup 1.0000x reference)
//
#include <hip/hip_runtime.h>

// ROI Align (max mode) — matches the JAX/numpy reference exactly.
// feature: (B=2, C=256, H=200, W=304) fp32
// boxes:   (N=512, 4) fp32   [x1,y1,x2,y2] in image coords
// batch_idx: (N,) int32
// out:     (N, C, 7, 7) fp32
//
// SPATIAL_SCALE=0.25, POOLED=7, SAMPLING_RATIO=2, MODE=max.
// Invalid samples (unclipped coord outside (-1,H)/(−1,W)) contribute 0.0 to
// the max — features can be negative, so this is semantically significant.

#define SPATIAL_SCALE 0.25f
#define POOLED 7
#define SR 2

constexpr int Bc = 2;
constexpr int Cc = 256;
constexpr int Hc = 200;
constexpr int Wc = 304;
constexpr int Nc = 512;

__global__ __launch_bounds__(256) void roi_align_max_kernel(
    const float* __restrict__ feature,
    const float* __restrict__ boxes,
    const int*   __restrict__ batch_idx,
    float*       __restrict__ out,
    int total)
{
    int idx = blockIdx.x * blockDim.x + threadIdx.x;
    if (idx >= total) return;

    // Decode (n, c, ph, pw) — matches output memory layout, coalesced store.
    int pw = idx % POOLED;
    int ph = (idx / POOLED) % POOLED;
    int c  = (idx / (POOLED * POOLED)) % Cc;
    int n  = idx / (POOLED * POOLED * Cc);

    // Box → ROI in feature coords. *0.25f is exact (power of two).
    float rsx = boxes[n * 4 + 0] * SPATIAL_SCALE;
    float rsy = boxes[n * 4 + 1] * SPATIAL_SCALE;
    float rex = boxes[n * 4 + 2] * SPATIAL_SCALE;
    float rey = boxes[n * 4 + 3] * SPATIAL_SCALE;
    float roi_w = fmaxf(rex - rsx, 1.0f);
    float roi_h = fmaxf(rey - rsy, 1.0f);
    float bin_w = roi_w / (float)POOLED;
    float bin_h = roi_h / (float)POOLED;

    int b = batch_idx[n];
    const float* __restrict__ fptr =
        feature + ((size_t)b * Cc + c) * (size_t)(Hc * Wc);

    // Precompute the 2 y-samples and 2 x-samples for this pooled cell.
    // Use non-contracted mul+add so floorf boundaries match numpy exactly.
    int   y0i[SR], y1i[SR], x0i[SR], x1i[SR];
    float ly[SR], hy[SR], lx[SR], hx[SR];
    bool  vy[SR], vx[SR];

    #pragma unroll
    for (int s = 0; s < SR; ++s) {
        float sval = ((float)s + 0.5f) / (float)SR;      // 0.25, 0.75 exact
        // y = rsy + (ph + sval) * bin_h  — same op order as reference
        float py = (float)ph + sval;                      // exact
        float y  = __fadd_rn(rsy, __fmul_rn(py, bin_h));
        vy[s] = (y > -1.0f) && (y < (float)Hc);
        float yc = fminf(fmaxf(y, 0.0f), (float)(Hc - 1));
        int yf = (int)floorf(yc);
        y0i[s] = yf;
        y1i[s] = min(yf + 1, Hc - 1);
        ly[s]  = yc - (float)yf;
        hy[s]  = 1.0f - ly[s];

        float px = (float)pw + sval;
        float x  = __fadd_rn(rsx, __fmul_rn(px, bin_w));
        vx[s] = (x > -1.0f) && (x < (float)Wc);
        float xc = fminf(fmaxf(x, 0.0f), (float)(Wc - 1));
        int xf = (int)floorf(xc);
        x0i[s] = xf;
        x1i[s] = min(xf + 1, Wc - 1);
        lx[s]  = xc - (float)xf;
        hx[s]  = 1.0f - lx[s];
    }

    float m = -INFINITY;
    #pragma unroll
    for (int sy = 0; sy < SR; ++sy) {
        int r0 = y0i[sy] * Wc;
        int r1 = y1i[sy] * Wc;
        #pragma unroll
        for (int sx = 0; sx < SR; ++sx) {
            float v00 = fptr[r0 + x0i[sx]];
            float v01 = fptr[r0 + x1i[sx]];
            float v10 = fptr[r1 + x0i[sx]];
            float v11 = fptr[r1 + x1i[sx]];
            float bil = hy[sy] * hx[sx] * v00 + hy[sy] * lx[sx] * v01 +
                        ly[sy] * hx[sx] * v10 + ly[sy] * lx[sx] * v11;
            float v = (vy[sy] && vx[sx]) ? bil : 0.0f;
            m = fmaxf(m, v);
        }
    }

    out[idx] = m;
}

extern "C" void kernel_launch(void* const* d_in, const int* in_sizes, int n_in,
                              void* d_out, int out_size, void* d_ws, size_t ws_size,
                              hipStream_t stream) {
    const float* feature   = (const float*)d_in[0];
    const float* boxes     = (const float*)d_in[1];
    const int*   batch_idx = (const int*)d_in[2];
    float*       out       = (float*)d_out;

    int total = Nc * Cc * POOLED * POOLED;   // 6,422,528
    int block = 256;
    int grid  = (total + block - 1) / block; // 25,088
    roi_align_max_kernel<<<grid, block, 0, stream>>>(feature, boxes, batch_idx,
                                                     out, total);
}

// Round 2
// 261.415 us; speedup vs baseline: 1.0169x; 1.0169x over previous
//
#include <hip/hip_runtime.h>

// ROI Align (max mode) — matches the JAX/numpy reference exactly.
// feature: (B=2, C=256, H=200, W=304) fp32
// boxes:   (N=512, 4) fp32   [x1,y1,x2,y2] in image coords
// batch_idx: (N,) int32
// out:     (N, C, 7, 7) fp32
//
// R2 change: block-order swizzle. Natural order (n outer) gives each feature
// plane (b,c) a reuse distance of the whole 125 MB tensor -> L2 misses, 324 MB
// HBM fetch (R1 measured). Swizzled order (c-chunk outer, n inner) makes all
// 512 boxes reading the same ~6 channel planes temporally adjacent ->
// working set ~3 MB fits L2. Per-thread work & store pattern unchanged
// (stores stay fully coalesced).

#define SPATIAL_SCALE 0.25f
#define POOLED 7
#define SR 2

constexpr int Bc = 2;
constexpr int Cc = 256;
constexpr int Hc = 200;
constexpr int Wc = 304;
constexpr int Nc = 512;
constexpr int CELLS = POOLED * POOLED;          // 49
constexpr int PER_BOX = Cc * CELLS;             // 12544
constexpr int CHUNKS = PER_BOX / 256;           // 49 blocks of 256 per box

__global__ __launch_bounds__(256) void roi_align_max_kernel(
    const float* __restrict__ feature,
    const float* __restrict__ boxes,
    const int*   __restrict__ batch_idx,
    float*       __restrict__ out)
{
    // Swizzle: consecutive blocks share the same channel-chunk across boxes.
    int raw   = blockIdx.x;          // 0 .. 49*512-1
    int chunk = raw / Nc;            // 0..48  (which 256-element slice of a box)
    int n     = raw - chunk * Nc;    // 0..511 (box)
    int idx   = n * PER_BOX + chunk * 256 + threadIdx.x;  // output element

    // Decode (c, ph, pw) within the box.
    int rem = idx - n * PER_BOX;     // 0..12543
    int pw  = rem % POOLED;
    int ph  = (rem / POOLED) % POOLED;
    int c   = rem / CELLS;

    // Box → ROI in feature coords. *0.25f is exact (power of two).
    float rsx = boxes[n * 4 + 0] * SPATIAL_SCALE;
    float rsy = boxes[n * 4 + 1] * SPATIAL_SCALE;
    float rex = boxes[n * 4 + 2] * SPATIAL_SCALE;
    float rey = boxes[n * 4 + 3] * SPATIAL_SCALE;
    float roi_w = fmaxf(rex - rsx, 1.0f);
    float roi_h = fmaxf(rey - rsy, 1.0f);
    float bin_w = roi_w / (float)POOLED;
    float bin_h = roi_h / (float)POOLED;

    int b = batch_idx[n];
    const float* __restrict__ fptr =
        feature + ((size_t)b * Cc + c) * (size_t)(Hc * Wc);

    // Precompute the 2 y-samples and 2 x-samples for this pooled cell.
    // Non-contracted mul+add so floorf boundaries match numpy exactly.
    int   y0i[SR], y1i[SR], x0i[SR], x1i[SR];
    float ly[SR], hy[SR], lx[SR], hx[SR];
    bool  vy[SR], vx[SR];

    #pragma unroll
    for (int s = 0; s < SR; ++s) {
        float sval = ((float)s + 0.5f) / (float)SR;      // 0.25, 0.75 exact
        float py = (float)ph + sval;                      // exact
        float y  = __fadd_rn(rsy, __fmul_rn(py, bin_h));
        vy[s] = (y > -1.0f) && (y < (float)Hc);
        float yc = fminf(fmaxf(y, 0.0f), (float)(Hc - 1));
        int yf = (int)floorf(yc);
        y0i[s] = yf;
        y1i[s] = min(yf + 1, Hc - 1);
        ly[s]  = yc - (float)yf;
        hy[s]  = 1.0f - ly[s];

        float px = (float)pw + sval;
        float x  = __fadd_rn(rsx, __fmul_rn(px, bin_w));
        vx[s] = (x > -1.0f) && (x < (float)Wc);
        float xc = fminf(fmaxf(x, 0.0f), (float)(Wc - 1));
        int xf = (int)floorf(xc);
        x0i[s] = xf;
        x1i[s] = min(xf + 1, Wc - 1);
        lx[s]  = xc - (float)xf;
        hx[s]  = 1.0f - lx[s];
    }

    float m = -INFINITY;
    #pragma unroll
    for (int sy = 0; sy < SR; ++sy) {
        int r0 = y0i[sy] * Wc;
        int r1 = y1i[sy] * Wc;
        #pragma unroll
        for (int sx = 0; sx < SR; ++sx) {
            float v00 = fptr[r0 + x0i[sx]];
            float v01 = fptr[r0 + x1i[sx]];
            float v10 = fptr[r1 + x0i[sx]];
            float v11 = fptr[r1 + x1i[sx]];
            float bil = hy[sy] * hx[sx] * v00 + hy[sy] * lx[sx] * v01 +
                        ly[sy] * hx[sx] * v10 + ly[sy] * lx[sx] * v11;
            float v = (vy[sy] && vx[sx]) ? bil : 0.0f;
            m = fmaxf(m, v);
        }
    }

    out[idx] = m;
}

extern "C" void kernel_launch(void* const* d_in, const int* in_sizes, int n_in,
                              void* d_out, int out_size, void* d_ws, size_t ws_size,
                              hipStream_t stream) {
    const float* feature   = (const float*)d_in[0];
    const float* boxes     = (const float*)d_in[1];
    const int*   batch_idx = (const int*)d_in[2];
    float*       out       = (float*)d_out;

    int grid  = Nc * CHUNKS;   // 512 * 49 = 25088 blocks of 256
    roi_align_max_kernel<<<grid, 256, 0, stream>>>(feature, boxes, batch_idx, out);
}

// Round 3
// 227.758 us; speedup vs baseline: 1.1672x; 1.1478x over previous
//
#include <hip/hip_runtime.h>

// ROI Align (max) — R3: LDS row-staging to kill gather transaction serialization.
//
// R2 evidence: FETCH fell 324->236 MB but dur stayed 127 us; HBM BW only 26%.
// Bottleneck = per-wave scattered gathers (~80M serialized L1 line transactions
// ~= 130 us). Fix: block per (box, 4-channel group); stage the 28 needed sample
// rows x 64-wide aligned x-span per channel into LDS with float4 lane-contiguous
// loads (each wave-load touches ~17 lines vs ~50 scattered), then compute the
// 16-tap bilinear max from LDS. x-span <= ~54 (box width <= 208 img px * 0.25
// = 52 feature px), so 64 columns always suffice.
//
// feature: (2, 256, 200, 304) fp32; boxes: (512,4); batch_idx: (512,) i32
// out: (512, 256, 7, 7) fp32. SPATIAL_SCALE=0.25, POOLED=7, SR=2, MODE=max.

#define SPATIAL_SCALE 0.25f
#define POOLED 7
#define SR 2

constexpr int Bc = 2;
constexpr int Cc = 256;
constexpr int Hc = 200;
constexpr int Wc = 304;
constexpr int Nc = 512;

constexpr int CG      = 4;               // channels per block
constexpr int NSAMP   = POOLED * SR;     // 14 sample coords per axis
constexpr int NROW    = NSAMP * 2;       // 28 row slots (y0,y1 per sample)
constexpr int XW      = 64;              // staged columns (16 float4 lanes)
constexpr int XPAD    = 68;              // LDS row stride, floats (16B-aligned, bank-rotating)
constexpr int CH_STR  = NROW * XPAD;     // 1904 floats per channel
constexpr int CELLS   = POOLED * POOLED; // 49
constexpr int OUTS    = CG * CELLS;      // 196 outputs per block
constexpr int PER_BOX = Cc * CELLS;      // 12544
constexpr int PLANE   = Hc * Wc;         // 60800

__global__ __launch_bounds__(256) void roi_align_max_kernel(
    const float* __restrict__ feature,
    const float* __restrict__ boxes,
    const int*   __restrict__ batch_idx,
    float*       __restrict__ out)
{
    __shared__ float lds[CG * CH_STR];   // 30,464 B -> 5 blocks/CU

    int bid = blockIdx.x;
    int cg  = bid / Nc;                  // channel group 0..63 (outer: L2 reuse across boxes)
    int n   = bid - cg * Nc;             // box 0..511
    int tid = threadIdx.x;

    // ---- Box math (block-uniform; boxes[n] loads scalarize) ----
    float rsx = boxes[n * 4 + 0] * SPATIAL_SCALE;
    float rsy = boxes[n * 4 + 1] * SPATIAL_SCALE;
    float rex = boxes[n * 4 + 2] * SPATIAL_SCALE;
    float rey = boxes[n * 4 + 3] * SPATIAL_SCALE;
    float roi_w = fmaxf(rex - rsx, 1.0f);
    float roi_h = fmaxf(rey - rsy, 1.0f);
    float bin_w = roi_w / (float)POOLED;
    float bin_h = roi_h / (float)POOLED;
    int b = batch_idx[n];

    // xbase: aligned-down floor of the first (smallest) x sample. Samples are
    // monotone in index, so all needed columns are in [xbase, xbase+63].
    float x_first = __fadd_rn(rsx, __fmul_rn(0.25f, bin_w)); // (0+0.5)/2 * bin_w
    float xc0 = fminf(fmaxf(x_first, 0.0f), (float)(Wc - 1));
    int xbase = ((int)floorf(xc0)) & ~3;

    const float* __restrict__ gbase =
        feature + ((size_t)b * Cc + (size_t)cg * CG) * (size_t)PLANE;

    // ---- Staging: CG*NROW = 112 row segments, 16 float4-lanes each ----
    int lane16 = tid & 15;
    int rbase  = tid >> 4;               // 0..15
    #pragma unroll
    for (int it = 0; it < 7; ++it) {
        int r       = it * 16 + rbase;   // 0..111
        int c_local = r / NROW;
        int slot    = r - c_local * NROW; // 0..27
        int s       = slot >> 1;          // sample 0..13
        int which   = slot & 1;           // 0 -> y0 row, 1 -> y1 row
        int p       = s >> 1;             // pooled index 0..6
        int sub     = s & 1;              // sub-sample 0..1
        // y = rsy + (p + (sub+0.5)/2) * bin_h  — same float expr as compute phase
        float py = (float)p + ((float)sub + 0.5f) * 0.5f;
        float fy = __fadd_rn(rsy, __fmul_rn(py, bin_h));
        float fyc = fminf(fmaxf(fy, 0.0f), (float)(Hc - 1));
        int y0 = (int)floorf(fyc);
        int row = which ? min(y0 + 1, Hc - 1) : y0;

        int col = xbase + lane16 * 4;
        col = min(col, Wc - 4);           // clamp: clamped positions are never read
        const float4 v = *(const float4*)(gbase + (size_t)c_local * PLANE
                                          + row * Wc + col);
        *(float4*)&lds[c_local * CH_STR + slot * XPAD + lane16 * 4] = v;
    }
    __syncthreads();

    // ---- Compute: 196 outputs (4 channels x 49 cells), one per thread ----
    if (tid < OUTS) {
        int c_local = tid / CELLS;
        int cell    = tid - c_local * CELLS;
        int ph      = cell / POOLED;
        int pw      = cell - ph * POOLED;
        const float* __restrict__ L = &lds[c_local * CH_STR];

        float m = -INFINITY;
        #pragma unroll
        for (int sy = 0; sy < SR; ++sy) {
            int sY = ph * SR + sy;        // sample index 0..13
            float py = (float)ph + ((float)sy + 0.5f) * 0.5f;
            float fy = __fadd_rn(rsy, __fmul_rn(py, bin_h));
            bool vy = (fy > -1.0f) && (fy < (float)Hc);
            float fyc = fminf(fmaxf(fy, 0.0f), (float)(Hc - 1));
            int y0 = (int)floorf(fyc);
            float ly = fyc - (float)y0;
            float hy = 1.0f - ly;
            const float* __restrict__ r0 = L + (2 * sY) * XPAD;
            const float* __restrict__ r1 = L + (2 * sY + 1) * XPAD;

            #pragma unroll
            for (int sx = 0; sx < SR; ++sx) {
                float px = (float)pw + ((float)sx + 0.5f) * 0.5f;
                float fx = __fadd_rn(rsx, __fmul_rn(px, bin_w));
                bool vx = (fx > -1.0f) && (fx < (float)Wc);
                float fxc = fminf(fmaxf(fx, 0.0f), (float)(Wc - 1));
                int x0 = (int)floorf(fxc);
                float lx = fxc - (float)x0;
                float hx = 1.0f - lx;
                int c0 = x0 - xbase;
                int x1 = min(x0 + 1, Wc - 1);
                int c1 = x1 - xbase;

                float v00 = r0[c0], v01 = r0[c1];
                float v10 = r1[c0], v11 = r1[c1];
                float bil = hy * hx * v00 + hy * lx * v01 +
                            ly * hx * v10 + ly * lx * v11;
                float v = (vy && vx) ? bil : 0.0f;
                m = fmaxf(m, v);
            }
        }
        out[(size_t)n * PER_BOX + cg * OUTS + tid] = m;
    }
}

extern "C" void kernel_launch(void* const* d_in, const int* in_sizes, int n_in,
                              void* d_out, int out_size, void* d_ws, size_t ws_size,
                              hipStream_t stream) {
    const float* feature   = (const float*)d_in[0];
    const float* boxes     = (const float*)d_in[1];
    const int*   batch_idx = (const int*)d_in[2];
    float*       out       = (float*)d_out;

    int grid = (Cc / CG) * Nc;           // 64 * 512 = 32768 blocks
    roi_align_max_kernel<<<grid, 256, 0, stream>>>(feature, boxes, batch_idx, out);
}